// Round 4
// baseline (214.050 us; speedup 1.0000x reference)
//
#include <hip/hip_runtime.h>

#define NROWS 4096
#define DDIM  256
#define K2    768          // augmented K: [hi|hi|lo] x [hi|lo|hi]
#define MARGIN 0.1f
#define GRID_MAIN 1024

typedef __attribute__((ext_vector_type(4)))  _Float16 half4;
typedef __attribute__((ext_vector_type(8)))  _Float16 half8;
typedef __attribute__((ext_vector_type(16))) float    floatx16;

__device__ inline void load_lds16(const void* g, void* l) {
  __builtin_amdgcn_global_load_lds((const __attribute__((address_space(1))) void*)g,
                                   (__attribute__((address_space(3))) void*)l,
                                   16, 0, 0);
}

// ================= PATH A =================

// ---- A1: pack A'=[Vhi|Vhi|Vlo], B'=[Thi|Tlo|Thi]; diag; zero accumulators ----
__global__ __launch_bounds__(256) void convert_diag_kernel(
    const float* __restrict__ v, const float* __restrict__ t,
    _Float16* __restrict__ Ap, _Float16* __restrict__ Bp,
    float* __restrict__ diag, int* __restrict__ rank, float* __restrict__ sums,
    int* __restrict__ done) {
  const int w    = threadIdx.x >> 6;
  const int lane = threadIdx.x & 63;
  const int row  = blockIdx.x * 4 + w;
  const size_t base = (size_t)row * DDIM;
  const float4 a = ((const float4*)(v + base))[lane];
  const float4 b = ((const float4*)(t + base))[lane];
  half4 ah, al, bh, bl;
  ah.x = (_Float16)a.x; al.x = (_Float16)(a.x - (float)ah.x);
  ah.y = (_Float16)a.y; al.y = (_Float16)(a.y - (float)ah.y);
  ah.z = (_Float16)a.z; al.z = (_Float16)(a.z - (float)ah.z);
  ah.w = (_Float16)a.w; al.w = (_Float16)(a.w - (float)ah.w);
  bh.x = (_Float16)b.x; bl.x = (_Float16)(b.x - (float)bh.x);
  bh.y = (_Float16)b.y; bl.y = (_Float16)(b.y - (float)bh.y);
  bh.z = (_Float16)b.z; bl.z = (_Float16)(b.z - (float)bh.z);
  bh.w = (_Float16)b.w; bl.w = (_Float16)(b.w - (float)bh.w);
  _Float16* ar = Ap + (size_t)row * K2;
  _Float16* br = Bp + (size_t)row * K2;
  *(half4*)(ar + 4 * lane)       = ah;
  *(half4*)(ar + 256 + 4 * lane) = ah;
  *(half4*)(ar + 512 + 4 * lane) = al;
  *(half4*)(br + 4 * lane)       = bh;
  *(half4*)(br + 256 + 4 * lane) = bl;
  *(half4*)(br + 512 + 4 * lane) = bh;
  float s = a.x*b.x + a.y*b.y + a.z*b.z + a.w*b.w;
  #pragma unroll
  for (int off = 32; off; off >>= 1) s += __shfl_down(s, off);
  if (lane == 0) { diag[row] = s; rank[row] = 0; }
  if (blockIdx.x == 0 && threadIdx.x < 4) {
    if (threadIdx.x < 2) sums[threadIdx.x] = 0.f;
    if (threadIdx.x == 2) *done = 0;
  }
}

// ---- A2: m97-style f16 GEMM (128x128 tile, BK=64, global_load_lds) + epilogue
//          + fused final reduction in the last-finishing block ----
// LDS layout: 128 rows x 64 halves (128 B/row). Chunk c (16 B) of row r holds
// global chunk c ^ (r & 7)  -> fragment ds_read_b128 spreads all 8 bank groups.
__global__ __launch_bounds__(256, 3) void main2(
    const _Float16* __restrict__ Ap, const _Float16* __restrict__ Bp,
    const float* __restrict__ diag, float* __restrict__ sums,
    int* __restrict__ rank, int* __restrict__ done, float* __restrict__ out) {
  __shared__ __align__(16) _Float16 As[128 * 64];
  __shared__ __align__(16) _Float16 Bs[128 * 64];
  __shared__ float sdi[128];
  __shared__ float sdj[128];
  __shared__ int   is_last;

  const int tid  = threadIdx.x;
  const int w    = tid >> 6;
  const int lane = tid & 63;
  const int i0   = blockIdx.y * 128;
  const int j0   = blockIdx.x * 128;

  // ---- staging map: thread covers chunks q = r*256 + tid, r = 0..3 ----
  // LDS chunk q -> (row = q>>3, ch = q&7); global chunk = ch ^ (row&7).
  const _Float16* gA[4];
  const _Float16* gB[4];
  _Float16* lA[4];
  _Float16* lB[4];
  #pragma unroll
  for (int r = 0; r < 4; ++r) {
    const int q   = r * 256 + tid;
    const int row = q >> 3;
    const int chg = (q & 7) ^ (row & 7);
    gA[r] = Ap + (size_t)(i0 + row) * K2 + chg * 8;
    gB[r] = Bp + (size_t)(j0 + row) * K2 + chg * 8;
    // wave-uniform LDS base for this (r, w); HW adds lane*16
    lA[r] = As + (r * 256 + w * 64) * 8;
    lB[r] = Bs + (r * 256 + w * 64) * 8;
  }

  floatx16 acc[2][2];
  #pragma unroll
  for (int mt = 0; mt < 2; ++mt)
    #pragma unroll
    for (int nt = 0; nt < 2; ++nt)
      #pragma unroll
      for (int r = 0; r < 16; ++r) acc[mt][nt][r] = 0.f;

  // fragment addressing
  const int mw    = (w >> 1) * 64;
  const int nw    = (w & 1) * 64;
  const int rL    = lane & 31;           // row/col within 32-tile
  const int khsel = lane >> 5;           // 0/1 -> k sub-chunk

  #pragma unroll 1
  for (int slab = 0; slab < K2 / 64; ++slab) {
    __syncthreads();   // previous compute done reading LDS
    #pragma unroll
    for (int r = 0; r < 4; ++r) {
      load_lds16(gA[r] + slab * 64, lA[r]);
      load_lds16(gB[r] + slab * 64, lB[r]);
    }
    __syncthreads();   // staging complete (compiler drains vmcnt before barrier)

    #pragma unroll
    for (int ks = 0; ks < 4; ++ks) {
      half8 af[2], bf[2];
      #pragma unroll
      for (int mt = 0; mt < 2; ++mt) {
        const int row = mw + mt * 32 + rL;
        const int ch  = (ks * 2 + khsel) ^ (row & 7);
        af[mt] = *(const half8*)&As[row * 64 + ch * 8];
      }
      #pragma unroll
      for (int nt = 0; nt < 2; ++nt) {
        const int row = nw + nt * 32 + rL;
        const int ch  = (ks * 2 + khsel) ^ (row & 7);
        bf[nt] = *(const half8*)&Bs[row * 64 + ch * 8];
      }
      #pragma unroll
      for (int mt = 0; mt < 2; ++mt)
        #pragma unroll
        for (int nt = 0; nt < 2; ++nt)
          acc[mt][nt] = __builtin_amdgcn_mfma_f32_32x32x16_f16(af[mt], bf[nt], acc[mt][nt], 0, 0, 0);
    }
  }

  // ---- epilogue (C/D layout verified R2): col=lane&31, row=(reg&3)+8*(reg>>2)+4*(lane>>5) ----
  if (tid < 128) sdi[tid] = diag[i0 + tid];
  else           sdj[tid - 128] = diag[j0 + tid - 128];
  __syncthreads();

  float vt = 0.f, tv = 0.f;
  const int h = lane >> 5;
  #pragma unroll
  for (int mt = 0; mt < 2; ++mt) {
    const int rbase = mw + mt * 32;
    #pragma unroll
    for (int reg = 0; reg < 16; ++reg) {
      const int r  = (reg & 3) + 8 * (reg >> 2) + 4 * h;
      const int gi = i0 + rbase + r;
      const float di = sdi[rbase + r];
      unsigned long long b0 = 0, b1 = 0;
      #pragma unroll
      for (int nt = 0; nt < 2; ++nt) {
        const int cc = nw + nt * 32 + rL;
        const int gj = j0 + cc;
        const float s  = acc[mt][nt][reg];
        const float dj = sdj[cc];
        const bool ne = (gi != gj);
        if (ne) {
          vt += fmaxf(0.f, MARGIN - di + s);
          tv += fmaxf(0.f, MARGIN - dj + s);
        }
        const unsigned long long bb = __ballot(ne && (s > di));
        if (nt == 0) b0 = bb; else b1 = bb;
      }
      if (rL == 0) {
        const int cnt = h ? (int)(__popcll(b0 >> 32) + __popcll(b1 >> 32))
                          : (int)(__popcll(b0 & 0xFFFFFFFFull) + __popcll(b1 & 0xFFFFFFFFull));
        atomicAdd(&rank[gi], cnt);
      }
    }
  }
  #pragma unroll
  for (int off = 32; off; off >>= 1) {
    vt += __shfl_down(vt, off);
    tv += __shfl_down(tv, off);
  }
  if (lane == 0) {
    atomicAdd(&sums[0], vt);
    atomicAdd(&sums[1], tv);
  }

  // ---- fused final reduction: last-finishing block computes the 6 outputs ----
  __threadfence();
  __syncthreads();
  if (tid == 0) is_last = (atomicAdd(done, 1) == GRID_MAIN - 1);
  __syncthreads();
  if (!is_last) return;

  int c1 = 0, c5 = 0, c10 = 0, cs = 0;
  for (int i = tid; i < NROWS; i += 256) {
    const int r = atomicAdd(&rank[i], 0);   // device-scope coherent read
    c1  += (r < 1);
    c5  += (r < 5);
    c10 += (r < 10);
    cs  += r;
  }
  #pragma unroll
  for (int off = 32; off; off >>= 1) {
    c1  += __shfl_down(c1, off);
    c5  += __shfl_down(c5, off);
    c10 += __shfl_down(c10, off);
    cs  += __shfl_down(cs, off);
  }
  __shared__ int s1[4], s5[4], s10[4], ssm[4];
  if ((tid & 63) == 0) { s1[w] = c1; s5[w] = c5; s10[w] = c10; ssm[w] = cs; }
  __syncthreads();
  if (tid == 0) {
    int a1 = 0, a5 = 0, a10 = 0, as = 0;
    #pragma unroll
    for (int k = 0; k < 4; ++k) { a1 += s1[k]; a5 += s5[k]; a10 += s10[k]; as += ssm[k]; }
    const float denom = 4096.0f * 4095.0f;
    out[0] = atomicAdd(&sums[0], 0.f) / denom;
    out[1] = atomicAdd(&sums[1], 0.f) / denom;
    out[2] = a1  / 4096.0f;
    out[3] = a5  / 4096.0f;
    out[4] = a10 / 4096.0f;
    out[5] = (float)as / 4096.0f;
  }
}

// ================= PATH B (fallback, R2-verified) =================

__global__ __launch_bounds__(256) void diag_kernel(
    const float* __restrict__ v, const float* __restrict__ t,
    float* __restrict__ diag, int* __restrict__ rank, float* __restrict__ sums) {
  const int wv   = threadIdx.x >> 6;
  const int lane = threadIdx.x & 63;
  const int row  = blockIdx.x * 4 + wv;
  const float4 a = ((const float4*)(v + (size_t)row * DDIM))[lane];
  const float4 b = ((const float4*)(t + (size_t)row * DDIM))[lane];
  float s = a.x*b.x + a.y*b.y + a.z*b.z + a.w*b.w;
  #pragma unroll
  for (int off = 32; off; off >>= 1) s += __shfl_down(s, off);
  if (lane == 0) { diag[row] = s; rank[row] = 0; }
  if (blockIdx.x == 0 && threadIdx.x < 2) sums[threadIdx.x] = 0.f;
}

__device__ inline void stage4(_Float16* __restrict__ dhi, _Float16* __restrict__ dlo,
                              const float4 x) {
  half4 h, l;
  h.x = (_Float16)x.x; l.x = (_Float16)(x.x - (float)h.x);
  h.y = (_Float16)x.y; l.y = (_Float16)(x.y - (float)h.y);
  h.z = (_Float16)x.z; l.z = (_Float16)(x.z - (float)h.z);
  h.w = (_Float16)x.w; l.w = (_Float16)(x.w - (float)h.w);
  *(half4*)dhi = h;
  *(half4*)dlo = l;
}

__global__ __launch_bounds__(256, 2) void main_kernel(
    const float* __restrict__ v, const float* __restrict__ t,
    const float* __restrict__ diag, float* __restrict__ sums,
    int* __restrict__ rank) {
  __shared__ __align__(16) _Float16 Ahi[256 * 40];
  __shared__ __align__(16) _Float16 Alo[256 * 40];
  __shared__ __align__(16) _Float16 Bhi[128 * 40];
  __shared__ __align__(16) _Float16 Blo[128 * 40];
  __shared__ float sdi[256];
  __shared__ float sdj[128];

  const int tid  = threadIdx.x;
  const int w    = tid >> 6;
  const int lane = tid & 63;
  const int i0   = blockIdx.y * 256;
  const int j0   = blockIdx.x * 128;

  sdi[tid] = diag[i0 + tid];
  if (tid < 128) sdj[tid] = diag[j0 + tid];

  floatx16 acc[4][2];
  #pragma unroll
  for (int mt = 0; mt < 4; ++mt)
    #pragma unroll
    for (int nt = 0; nt < 2; ++nt)
      #pragma unroll
      for (int r = 0; r < 16; ++r) acc[mt][nt][r] = 0.f;

  const int srow = tid >> 3;
  const int skc  = (tid & 7) * 4;
  const float* vp = v + (size_t)(i0 + srow) * DDIM + skc;
  const float* tp = t + (size_t)(j0 + srow) * DDIM + skc;

  float4 pa[8], pb[4];
  #pragma unroll
  for (int p = 0; p < 8; ++p) pa[p] = *(const float4*)(vp + (size_t)p * 32 * DDIM);
  #pragma unroll
  for (int p = 0; p < 4; ++p) pb[p] = *(const float4*)(tp + (size_t)p * 32 * DDIM);

  const int mrow  = lane & 31;
  const int khalf = (lane >> 5) * 8;
  const int abase = ((w >> 1) * 128 + mrow) * 40 + khalf;
  const int bbase = ((w & 1) * 64 + mrow) * 40 + khalf;

  for (int s = 0; s < 8; ++s) {
    __syncthreads();
    #pragma unroll
    for (int p = 0; p < 8; ++p)
      stage4(&Ahi[(srow + p * 32) * 40 + skc], &Alo[(srow + p * 32) * 40 + skc], pa[p]);
    #pragma unroll
    for (int p = 0; p < 4; ++p)
      stage4(&Bhi[(srow + p * 32) * 40 + skc], &Blo[(srow + p * 32) * 40 + skc], pb[p]);
    __syncthreads();

    if (s < 7) {
      #pragma unroll
      for (int p = 0; p < 8; ++p)
        pa[p] = *(const float4*)(vp + (size_t)p * 32 * DDIM + (s + 1) * 32);
      #pragma unroll
      for (int p = 0; p < 4; ++p)
        pb[p] = *(const float4*)(tp + (size_t)p * 32 * DDIM + (s + 1) * 32);
    }

    #pragma unroll
    for (int ks = 0; ks < 2; ++ks) {
      half8 bh[2], bl[2];
      #pragma unroll
      for (int nt = 0; nt < 2; ++nt) {
        bh[nt] = *(const half8*)&Bhi[bbase + nt * 32 * 40 + ks * 16];
        bl[nt] = *(const half8*)&Blo[bbase + nt * 32 * 40 + ks * 16];
      }
      #pragma unroll
      for (int mt = 0; mt < 4; ++mt) {
        const half8 ah = *(const half8*)&Ahi[abase + mt * 32 * 40 + ks * 16];
        const half8 al = *(const half8*)&Alo[abase + mt * 32 * 40 + ks * 16];
        #pragma unroll
        for (int nt = 0; nt < 2; ++nt) {
          acc[mt][nt] = __builtin_amdgcn_mfma_f32_32x32x16_f16(al, bh[nt], acc[mt][nt], 0, 0, 0);
          acc[mt][nt] = __builtin_amdgcn_mfma_f32_32x32x16_f16(ah, bl[nt], acc[mt][nt], 0, 0, 0);
          acc[mt][nt] = __builtin_amdgcn_mfma_f32_32x32x16_f16(ah, bh[nt], acc[mt][nt], 0, 0, 0);
        }
      }
    }
  }

  float vt = 0.f, tv = 0.f;
  const int h    = lane >> 5;
  const int colL = lane & 31;
  #pragma unroll
  for (int mt = 0; mt < 4; ++mt) {
    const int rbase = (w >> 1) * 128 + mt * 32;
    #pragma unroll
    for (int reg = 0; reg < 16; ++reg) {
      const int r  = (reg & 3) + 8 * (reg >> 2) + 4 * h;
      const int gi = i0 + rbase + r;
      const float di = sdi[rbase + r];
      unsigned long long b0 = 0, b1 = 0;
      #pragma unroll
      for (int nt = 0; nt < 2; ++nt) {
        const int cc = (w & 1) * 64 + nt * 32 + colL;
        const int gj = j0 + cc;
        const float s  = acc[mt][nt][reg];
        const float dj = sdj[cc];
        const bool ne = (gi != gj);
        if (ne) {
          vt += fmaxf(0.f, MARGIN - di + s);
          tv += fmaxf(0.f, MARGIN - dj + s);
        }
        const unsigned long long bb = __ballot(ne && (s > di));
        if (nt == 0) b0 = bb; else b1 = bb;
      }
      if (colL == 0) {
        const int cnt = h ? (int)(__popcll(b0 >> 32) + __popcll(b1 >> 32))
                          : (int)(__popcll(b0 & 0xFFFFFFFFull) + __popcll(b1 & 0xFFFFFFFFull));
        atomicAdd(&rank[gi], cnt);
      }
    }
  }
  #pragma unroll
  for (int off = 32; off; off >>= 1) {
    vt += __shfl_down(vt, off);
    tv += __shfl_down(tv, off);
  }
  if (lane == 0) {
    atomicAdd(&sums[0], vt);
    atomicAdd(&sums[1], tv);
  }
}

__global__ __launch_bounds__(256) void final_kernel(
    const float* __restrict__ sums, const int* __restrict__ rank,
    float* __restrict__ out) {
  __shared__ int s1[4], s5[4], s10[4], ssum[4];
  const int tid = threadIdx.x;
  int c1 = 0, c5 = 0, c10 = 0, cs = 0;
  for (int i = tid; i < NROWS; i += 256) {
    const int r = rank[i];
    c1  += (r < 1);
    c5  += (r < 5);
    c10 += (r < 10);
    cs  += r;
  }
  #pragma unroll
  for (int off = 32; off; off >>= 1) {
    c1  += __shfl_down(c1, off);
    c5  += __shfl_down(c5, off);
    c10 += __shfl_down(c10, off);
    cs  += __shfl_down(cs, off);
  }
  const int w = tid >> 6;
  if ((tid & 63) == 0) { s1[w] = c1; s5[w] = c5; s10[w] = c10; ssum[w] = cs; }
  __syncthreads();
  if (tid == 0) {
    int a1 = 0, a5 = 0, a10 = 0, as = 0;
    for (int k = 0; k < 4; ++k) { a1 += s1[k]; a5 += s5[k]; a10 += s10[k]; as += ssum[k]; }
    const float denom = 4096.0f * 4095.0f;
    out[0] = sums[0] / denom;
    out[1] = sums[1] / denom;
    out[2] = a1  / 4096.0f;
    out[3] = a5  / 4096.0f;
    out[4] = a10 / 4096.0f;
    out[5] = (float)as / 4096.0f;
  }
}

extern "C" void kernel_launch(void* const* d_in, const int* in_sizes, int n_in,
                              void* d_out, int out_size, void* d_ws, size_t ws_size,
                              hipStream_t stream) {
  const float* v = (const float*)d_in[0];
  const float* t = (const float*)d_in[1];
  float* out = (float*)d_out;

  const size_t PACK = (size_t)NROWS * K2 * sizeof(_Float16);   // 6 MB each
  const size_t NEED = 2 * PACK + 2 * (size_t)NROWS * 4 + 256;

  if (ws_size >= NEED) {
    _Float16* Ap = (_Float16*)d_ws;
    _Float16* Bp = (_Float16*)((char*)d_ws + PACK);
    float* diag = (float*)((char*)d_ws + 2 * PACK);
    int*   rank = (int*)((char*)d_ws + 2 * PACK + NROWS * 4);
    float* sums = (float*)((char*)d_ws + 2 * PACK + 2 * (size_t)NROWS * 4);
    int*   done = (int*)((char*)d_ws + 2 * PACK + 2 * (size_t)NROWS * 4 + 64);

    hipLaunchKernelGGL(convert_diag_kernel, dim3(NROWS / 4), dim3(256), 0, stream,
                       v, t, Ap, Bp, diag, rank, sums, done);
    hipLaunchKernelGGL(main2, dim3(32, 32), dim3(256), 0, stream,
                       Ap, Bp, diag, sums, rank, done, out);
  } else {
    float* diag = (float*)d_ws;
    int*   rank = (int*)((char*)d_ws + NROWS * sizeof(float));
    float* sums = (float*)((char*)d_ws + 2 * (size_t)NROWS * sizeof(float));

    hipLaunchKernelGGL(diag_kernel, dim3(NROWS / 4), dim3(256), 0, stream,
                       v, t, diag, rank, sums);
    hipLaunchKernelGGL(main_kernel, dim3(32, 16), dim3(256), 0, stream,
                       v, t, diag, sums, rank);
    hipLaunchKernelGGL(final_kernel, dim3(1), dim3(256), 0, stream, sums, rank, out);
  }
}

// Round 5
// 159.008 us; speedup vs baseline: 1.3462x; 1.3462x over previous
//
#include <hip/hip_runtime.h>

#define NROWS 4096
#define DDIM  256
#define MARGIN 0.1f
#define GRID_MAIN 512   // 32 j-tiles(128) x 16 i-tiles(256)

typedef __attribute__((ext_vector_type(4)))  _Float16 half4;
typedef __attribute__((ext_vector_type(8)))  _Float16 half8;
typedef __attribute__((ext_vector_type(16))) float    floatx16;

// ---------------- Kernel 1: diag + zero accumulators ----------------
__global__ __launch_bounds__(256) void diag_kernel(
    const float* __restrict__ v, const float* __restrict__ t,
    float* __restrict__ diag, int* __restrict__ rank, float* __restrict__ sums,
    int* __restrict__ done) {
  const int wv   = threadIdx.x >> 6;
  const int lane = threadIdx.x & 63;
  const int row  = blockIdx.x * 4 + wv;
  const float4 a = ((const float4*)(v + (size_t)row * DDIM))[lane];
  const float4 b = ((const float4*)(t + (size_t)row * DDIM))[lane];
  float s = a.x*b.x + a.y*b.y + a.z*b.z + a.w*b.w;
  #pragma unroll
  for (int off = 32; off; off >>= 1) s += __shfl_down(s, off);
  if (lane == 0) { diag[row] = s; rank[row] = 0; }
  if (blockIdx.x == 0 && threadIdx.x < 4) {
    if (threadIdx.x < 2) sums[threadIdx.x] = 0.f;
    if (threadIdx.x == 2) *done = 0;
  }
}

// fp32 -> (hi, lo) fp16 split, RNE both. x = hi + lo to ~2^-22 rel.
__device__ inline void stage4(_Float16* __restrict__ dhi, _Float16* __restrict__ dlo,
                              const float4 x) {
  half4 h, l;
  h.x = (_Float16)x.x; l.x = (_Float16)(x.x - (float)h.x);
  h.y = (_Float16)x.y; l.y = (_Float16)(x.y - (float)h.y);
  h.z = (_Float16)x.z; l.z = (_Float16)(x.z - (float)h.z);
  h.w = (_Float16)x.w; l.w = (_Float16)(x.w - (float)h.w);
  *(half4*)dhi = h;
  *(half4*)dlo = l;
}

// ---------------- Kernel 2: fused MFMA GEMM + epilogue + finale ----------------
// R2-verified structure: 256(i) x 128(j) block tile, 4 waves of 128x64,
// 32x32x16 f16 MFMA, 3-term hi/lo split, K-slab 32, LDS stride 40 halves.
// CHANGE vs R2: term-major MFMA order (8 independent MFMAs between reuses
// of any accumulator) + last-block fused final reduction (R4-verified).
__global__ __launch_bounds__(256, 2) void main_kernel(
    const float* __restrict__ v, const float* __restrict__ t,
    const float* __restrict__ diag, float* __restrict__ sums,
    int* __restrict__ rank, int* __restrict__ done, float* __restrict__ out) {
  __shared__ __align__(16) _Float16 Ahi[256 * 40];
  __shared__ __align__(16) _Float16 Alo[256 * 40];
  __shared__ __align__(16) _Float16 Bhi[128 * 40];
  __shared__ __align__(16) _Float16 Blo[128 * 40];
  __shared__ float sdi[256];
  __shared__ float sdj[128];
  __shared__ int   is_last;

  const int tid  = threadIdx.x;
  const int w    = tid >> 6;
  const int lane = tid & 63;
  const int i0   = blockIdx.y * 256;
  const int j0   = blockIdx.x * 128;

  sdi[tid] = diag[i0 + tid];
  if (tid < 128) sdj[tid] = diag[j0 + tid];

  floatx16 acc[4][2];
  #pragma unroll
  for (int mt = 0; mt < 4; ++mt)
    #pragma unroll
    for (int nt = 0; nt < 2; ++nt)
      #pragma unroll
      for (int r = 0; r < 16; ++r) acc[mt][nt][r] = 0.f;

  const int srow = tid >> 3;
  const int skc  = (tid & 7) * 4;
  const float* vp = v + (size_t)(i0 + srow) * DDIM + skc;
  const float* tp = t + (size_t)(j0 + srow) * DDIM + skc;

  float4 pa[8], pb[4];
  #pragma unroll
  for (int p = 0; p < 8; ++p) pa[p] = *(const float4*)(vp + (size_t)p * 32 * DDIM);
  #pragma unroll
  for (int p = 0; p < 4; ++p) pb[p] = *(const float4*)(tp + (size_t)p * 32 * DDIM);

  const int mrow  = lane & 31;
  const int khalf = (lane >> 5) * 8;
  const int abase = ((w >> 1) * 128 + mrow) * 40 + khalf;
  const int bbase = ((w & 1) * 64 + mrow) * 40 + khalf;

  for (int s = 0; s < 8; ++s) {
    __syncthreads();   // previous compute done reading LDS
    #pragma unroll
    for (int p = 0; p < 8; ++p)
      stage4(&Ahi[(srow + p * 32) * 40 + skc], &Alo[(srow + p * 32) * 40 + skc], pa[p]);
    #pragma unroll
    for (int p = 0; p < 4; ++p)
      stage4(&Bhi[(srow + p * 32) * 40 + skc], &Blo[(srow + p * 32) * 40 + skc], pb[p]);
    __syncthreads();

    if (s < 7) {   // prefetch next slab; overlaps with MFMA below
      #pragma unroll
      for (int p = 0; p < 8; ++p)
        pa[p] = *(const float4*)(vp + (size_t)p * 32 * DDIM + (s + 1) * 32);
      #pragma unroll
      for (int p = 0; p < 4; ++p)
        pb[p] = *(const float4*)(tp + (size_t)p * 32 * DDIM + (s + 1) * 32);
    }

    #pragma unroll
    for (int ks = 0; ks < 2; ++ks) {
      // load ALL fragments for this k-step first
      half8 ah[4], al[4], bh[2], bl[2];
      #pragma unroll
      for (int nt = 0; nt < 2; ++nt) {
        bh[nt] = *(const half8*)&Bhi[bbase + nt * 32 * 40 + ks * 16];
        bl[nt] = *(const half8*)&Blo[bbase + nt * 32 * 40 + ks * 16];
      }
      #pragma unroll
      for (int mt = 0; mt < 4; ++mt) {
        ah[mt] = *(const half8*)&Ahi[abase + mt * 32 * 40 + ks * 16];
        al[mt] = *(const half8*)&Alo[abase + mt * 32 * 40 + ks * 16];
      }
      // term-major: 8 independent MFMAs between reuses of any accumulator
      #pragma unroll
      for (int mt = 0; mt < 4; ++mt)
        #pragma unroll
        for (int nt = 0; nt < 2; ++nt)
          acc[mt][nt] = __builtin_amdgcn_mfma_f32_32x32x16_f16(al[mt], bh[nt], acc[mt][nt], 0, 0, 0);
      #pragma unroll
      for (int mt = 0; mt < 4; ++mt)
        #pragma unroll
        for (int nt = 0; nt < 2; ++nt)
          acc[mt][nt] = __builtin_amdgcn_mfma_f32_32x32x16_f16(ah[mt], bl[nt], acc[mt][nt], 0, 0, 0);
      #pragma unroll
      for (int mt = 0; mt < 4; ++mt)
        #pragma unroll
        for (int nt = 0; nt < 2; ++nt)
          acc[mt][nt] = __builtin_amdgcn_mfma_f32_32x32x16_f16(ah[mt], bh[nt], acc[mt][nt], 0, 0, 0);
    }
  }

  // ---- epilogue (C/D layout verified R2): col=lane&31, row=(reg&3)+8*(reg>>2)+4*(lane>>5) ----
  float vt = 0.f, tv = 0.f;
  const int h    = lane >> 5;
  const int colL = lane & 31;
  #pragma unroll
  for (int mt = 0; mt < 4; ++mt) {
    const int rbase = (w >> 1) * 128 + mt * 32;
    #pragma unroll
    for (int reg = 0; reg < 16; ++reg) {
      const int r  = (reg & 3) + 8 * (reg >> 2) + 4 * h;
      const int gi = i0 + rbase + r;
      const float di = sdi[rbase + r];
      unsigned long long b0 = 0, b1 = 0;
      #pragma unroll
      for (int nt = 0; nt < 2; ++nt) {
        const int cc = (w & 1) * 64 + nt * 32 + colL;
        const int gj = j0 + cc;
        const float s  = acc[mt][nt][reg];
        const float dj = sdj[cc];
        const bool ne = (gi != gj);
        if (ne) {
          vt += fmaxf(0.f, MARGIN - di + s);
          tv += fmaxf(0.f, MARGIN - dj + s);
        }
        const unsigned long long bb = __ballot(ne && (s > di));
        if (nt == 0) b0 = bb; else b1 = bb;
      }
      if (colL == 0) {
        const int cnt = h ? (int)(__popcll(b0 >> 32) + __popcll(b1 >> 32))
                          : (int)(__popcll(b0 & 0xFFFFFFFFull) + __popcll(b1 & 0xFFFFFFFFull));
        atomicAdd(&rank[gi], cnt);
      }
    }
  }
  #pragma unroll
  for (int off = 32; off; off >>= 1) {
    vt += __shfl_down(vt, off);
    tv += __shfl_down(tv, off);
  }
  if (lane == 0) {
    atomicAdd(&sums[0], vt);
    atomicAdd(&sums[1], tv);
  }

  // ---- fused final reduction (R4-verified): last-finishing block ----
  __threadfence();
  __syncthreads();
  if (tid == 0) is_last = (atomicAdd(done, 1) == GRID_MAIN - 1);
  __syncthreads();
  if (!is_last) return;

  int c1 = 0, c5 = 0, c10 = 0, cs = 0;
  for (int i = tid; i < NROWS; i += 256) {
    const int r = atomicAdd(&rank[i], 0);   // device-scope coherent read
    c1  += (r < 1);
    c5  += (r < 5);
    c10 += (r < 10);
    cs  += r;
  }
  #pragma unroll
  for (int off = 32; off; off >>= 1) {
    c1  += __shfl_down(c1, off);
    c5  += __shfl_down(c5, off);
    c10 += __shfl_down(c10, off);
    cs  += __shfl_down(cs, off);
  }
  __shared__ int s1[4], s5[4], s10[4], ssm[4];
  if ((tid & 63) == 0) { s1[w] = c1; s5[w] = c5; s10[w] = c10; ssm[w] = cs; }
  __syncthreads();
  if (tid == 0) {
    int a1 = 0, a5 = 0, a10 = 0, as = 0;
    #pragma unroll
    for (int k = 0; k < 4; ++k) { a1 += s1[k]; a5 += s5[k]; a10 += s10[k]; as += ssm[k]; }
    const float denom = 4096.0f * 4095.0f;
    out[0] = atomicAdd(&sums[0], 0.f) / denom;
    out[1] = atomicAdd(&sums[1], 0.f) / denom;
    out[2] = a1  / 4096.0f;
    out[3] = a5  / 4096.0f;
    out[4] = a10 / 4096.0f;
    out[5] = (float)as / 4096.0f;
  }
}

extern "C" void kernel_launch(void* const* d_in, const int* in_sizes, int n_in,
                              void* d_out, int out_size, void* d_ws, size_t ws_size,
                              hipStream_t stream) {
  const float* v = (const float*)d_in[0];
  const float* t = (const float*)d_in[1];
  float* out = (float*)d_out;

  // ws: diag 16KB | rank 16KB | sums 8B | done (at +64B)
  float* diag = (float*)d_ws;
  int*   rank = (int*)((char*)d_ws + NROWS * sizeof(float));
  float* sums = (float*)((char*)d_ws + 2 * (size_t)NROWS * sizeof(float));
  int*   done = (int*)((char*)d_ws + 2 * (size_t)NROWS * sizeof(float) + 64);

  hipLaunchKernelGGL(diag_kernel, dim3(NROWS / 4), dim3(256), 0, stream,
                     v, t, diag, rank, sums, done);
  hipLaunchKernelGGL(main_kernel, dim3(32, 16), dim3(256), 0, stream,
                     v, t, diag, sums, rank, done, out);
}